// Round 10
// baseline (192.397 us; speedup 1.0000x reference)
//
#include <hip/hip_runtime.h>
#include <hip/hip_fp16.h>

#define N_NODES 50000
#define D 128
#define HALF 64
#define E_EDGES 625000
#define CAP 64                                       // bucket capacity (max deg ~35)
#define M_BLK 64
#define NODE64_GRID ((N_NODES + M_BLK - 1) / M_BLK)  // 782

// --- radix partition geometry ---
#define NBINS 196                                    // bins of 256 nodes: bin = dst>>8
#define BIN_NODES 256
#define BINCAP 4096                                  // per-bin capacity (mean ~3200, +14 sigma)
#define GA 98                                        // partition blocks per edge set
#define CHUNK ((E_EDGES + GA - 1) / GA)              // 6379 edges per block
#define PARTA_GRID (2 * GA)                          // 196

typedef unsigned short ushortT;
typedef unsigned int uintT;
using f16     = _Float16;
using half8   = __attribute__((ext_vector_type(8))) _Float16;
using half4v  = __attribute__((ext_vector_type(4))) _Float16;
using floatx4 = __attribute__((ext_vector_type(4))) float;

__device__ __forceinline__ int rfl(int v) { return __builtin_amdgcn_readfirstlane(v); }
__device__ __forceinline__ floatx4 mfma16(half8 a, half8 b, floatx4 c) {
    return __builtin_amdgcn_mfma_f32_16x16x32_f16(a, b, c, 0, 0, 0);
}

// A-fragment read from swizzled wave-private LDS tile [16 rows][128 f16].
// Swizzle: 16B chunk cc stored at chunk (cc ^ (row&7)).
__device__ __forceinline__ half8 ldsA(const f16 (*Xw)[D], int lane, int ks) {
    int r = lane & 15;
    int cc = ks * 4 + (lane >> 4);
    return *(const half8*)&Xw[r][((cc ^ (r & 7)) << 3)];
}

// Stage 16 fp32 rows -> fp16 swizzled LDS (wave-private).
__device__ __forceinline__ void stage_f32(f16 (*Xw)[D], const float* __restrict__ X,
                                          int nodeBase, int lane) {
#pragma unroll
    for (int r4 = 0; r4 < 8; ++r4) {
        int s = lane + 64 * r4;            // 512 float4 slots = 16 rows x 32
        int row = s >> 5, c4 = s & 31;
        int nn = nodeBase + row; if (nn > N_NODES - 1) nn = N_NODES - 1;
        float4 v = *(const float4*)(X + (size_t)nn * D + c4 * 4);
        int cc = c4 >> 1;
        half4v pk = { (f16)v.x, (f16)v.y, (f16)v.z, (f16)v.w };
        *(half4v*)&Xw[row][((cc ^ (row & 7)) << 3) + ((c4 & 1) << 2)] = pk;
    }
}

// Stage 16 fp16 rows -> swizzled LDS (16B chunks).
__device__ __forceinline__ void stage_f16(f16 (*Xw)[D], const f16* __restrict__ X,
                                          int nodeBase, int lane) {
#pragma unroll
    for (int r = 0; r < 4; ++r) {
        int s = lane + 64 * r;             // 256 chunk slots = 16 rows x 16
        int row = s >> 4, cc = s & 15;
        int nn = nodeBase + row; if (nn > N_NODES - 1) nn = N_NODES - 1;
        uint4 v = *(const uint4*)(X + (size_t)nn * D + cc * 8);
        *(uint4*)&Xw[row][((cc ^ (row & 7)) << 3)] = v;
    }
}

// GEMM [16 x 128] = LDS-X @ packed-W(K=128), write fp16 result to Pout.
// (used by the co-scheduled transform in part_transform_kernel)
__device__ __forceinline__ void gemm_store_P(const f16 (*Xw)[D], const f16* __restrict__ Wp,
                                             f16* __restrict__ Pout, int nodeBase, int lane) {
    half8 a[4];
#pragma unroll
    for (int ks = 0; ks < 4; ++ks) a[ks] = ldsA(Xw, lane, ks);
#pragma unroll
    for (int ct = 0; ct < 8; ++ct) {
        floatx4 acc = {0.f, 0.f, 0.f, 0.f};
#pragma unroll
        for (int ks = 0; ks < 4; ++ks) {
            half8 b = *(const half8*)(Wp + (((ct * 4 + ks) * 64 + lane) << 3));
            acc = mfma16(a[ks], b, acc);
        }
        int col = ct * 16 + (lane & 15);
#pragma unroll
        for (int i = 0; i < 4; ++i) {
            int nn = nodeBase + (lane >> 4) * 4 + i;
            if (nn < N_NODES) Pout[(size_t)nn * D + col] = (f16)acc[i];
        }
    }
}

// prep: blocks 0..63 zero the 2*NBINS bin cursors; blocks 64..127 pack all six
// weight matrices into MFMA B-fragment order.
__global__ __launch_bounds__(256) void prep_kernel(
    int* __restrict__ gcur,
    const float* iWr0, const float* oWr0, const float* iWl1, const float* oWl1,
    const float* iWr1, const float* oWr1, const float* iWl0, const float* oWl0,
    const float* cW0, const float* cW1,
    f16* Wr0p, f16* Wl1p, f16* Wr1p, f16* Wl0p, f16* cW0p, f16* cW1p)
{
    int b = blockIdx.x;
    if (b < 64) {
        for (int i = b * 256 + threadIdx.x; i < 2 * NBINS; i += 64 * 256) gcur[i] = 0;
        return;
    }
    b -= 64;
    if (b < 32) {   // dual K=128 packs: 4 weights x 8 blocks
        int w = b >> 3;
        int e = (b & 7) * 256 + threadIdx.x;          // [0, 2048)
        const float* Wa; const float* Wb; f16* dst;
        if (w == 0)      { Wa = iWr0; Wb = oWr0; dst = Wr0p; }
        else if (w == 1) { Wa = iWl1; Wb = oWl1; dst = Wl1p; }
        else if (w == 2) { Wa = iWr1; Wb = oWr1; dst = Wr1p; }
        else             { Wa = iWl0; Wb = oWl0; dst = Wl0p; }
        int lane = e & 63, ks = (e >> 6) & 3, ct = e >> 8;
        int k0 = ks * 32 + ((lane >> 4) << 3), c = ct * 16 + (lane & 15);
        half8 v;
#pragma unroll
        for (int j = 0; j < 8; ++j) {
            int k = k0 + j;
            float f = (c < 64) ? Wa[k * HALF + c] : Wb[k * HALF + (c - 64)];
            v[j] = (f16)f;
        }
        *(half8*)(dst + ((size_t)e << 3)) = v;
        return;
    }
    b -= 32;        // cW K=256 packs: 2 weights x 16 blocks
    {
        int w = b >> 4;
        int e = (b & 15) * 256 + threadIdx.x;         // [0, 4096)
        const float* W = w ? cW1 : cW0;
        f16* dst = w ? cW1p : cW0p;
        int lane = e & 63, ks = (e >> 6) & 7, ct = e >> 9;
        int k0 = ks * 32 + ((lane >> 4) << 3), c = ct * 16 + (lane & 15);
        half8 v;
#pragma unroll
        for (int j = 0; j < 8; ++j) v[j] = (f16)W[(size_t)(k0 + j) * D + c];
        *(half8*)(dst + ((size_t)e << 3)) = v;
    }
}

// Heterogeneous launch:
//  blocks [0, PARTA_GRID): phase-A radix partition of one edge-set chunk —
//    LDS-staged edges, LDS histogram of 196 bins, ONE global atomic per
//    (block,bin) to reserve a range, then near-coalesced packed writes.
//  blocks [PARTA_GRID, +NODE64_GRID): MFMA transform P = X @ Wl0 (fp16).
__global__ __launch_bounds__(256) void part_transform_kernel(
    const int* __restrict__ ei_in, const int* __restrict__ ei_out,
    int* __restrict__ gcur, uintT* __restrict__ part,
    const float* __restrict__ X, const f16* __restrict__ Wl0p, f16* __restrict__ P)
{
    __shared__ __align__(16) char lraw[28032];
    const int tid = threadIdx.x;
    if ((int)blockIdx.x < PARTA_GRID) {
        uintT* le   = (uintT*)lraw;                       // 6400 x 4B
        int* cnt_l  = (int*)(lraw + 25600);               // 196
        int* base_l = cnt_l + NBINS;
        int* run_l  = base_l + NBINS;
        const int set = (int)blockIdx.x >= GA;
        const int b = blockIdx.x - (set ? GA : 0);
        const int* ei = set ? ei_out : ei_in;
        const int e0 = b * CHUNK;
        int n = E_EDGES - e0; if (n > CHUNK) n = CHUNK; if (n < 0) n = 0;
        for (int j = tid; j < n; j += 256) {
            int src = ei[e0 + j];
            int dst = ei[E_EDGES + e0 + j];
            le[j] = ((uintT)dst << 16) | (uintT)src;      // both < 2^16
        }
        for (int j = tid; j < NBINS; j += 256) cnt_l[j] = 0;
        __syncthreads();
        for (int j = tid; j < n; j += 256) atomicAdd(&cnt_l[le[j] >> 24], 1);  // bin = dst>>8
        __syncthreads();
        for (int j = tid; j < NBINS; j += 256) {
            int c = cnt_l[j];
            base_l[j] = c ? atomicAdd(&gcur[set * NBINS + j], c) : 0;
            run_l[j] = 0;
        }
        __syncthreads();
        uintT* pbase = part + (size_t)set * NBINS * BINCAP;
        for (int j = tid; j < n; j += 256) {
            uintT v = le[j];
            int bin = v >> 24;
            int pos = base_l[bin] + atomicAdd(&run_l[bin], 1);
            if (pos < BINCAP) pbase[(size_t)bin * BINCAP + pos] = v;
        }
        return;
    }
    // ---- transform part ----
    f16 (*Xh)[16][D] = (f16(*)[16][D])lraw;               // 4 x 16 x 128 f16 = 16 KB
    const int bid = blockIdx.x - PARTA_GRID;
    const int wave = tid >> 6, lane = tid & 63;
    const int nodeBase = bid * M_BLK + wave * 16;
    f16 (*Xw)[D] = Xh[wave];
    stage_f32(Xw, X, nodeBase, lane);
    gemm_store_P(Xw, Wl0p, P, nodeBase, lane);
}

// Phase B: one block per (bin, set). Build the 256-node bucket tile in LDS
// (LDS atomics only), then write counts + 32 KB tile fully coalesced.
__global__ __launch_bounds__(256) void bucket_build_kernel(
    const uintT* __restrict__ part, const int* __restrict__ gcur,
    int* __restrict__ cnt_in, int* __restrict__ cnt_out,
    ushortT* __restrict__ bkt_in, ushortT* __restrict__ bkt_out)
{
    __shared__ ushortT bk[BIN_NODES * CAP];   // 32 KB
    __shared__ int cl[BIN_NODES];
    const int tid = threadIdx.x;
    const int set = (int)blockIdx.x >= NBINS;
    const int bin = blockIdx.x - (set ? NBINS : 0);
    int total = gcur[set * NBINS + bin]; if (total > BINCAP) total = BINCAP;
    const uintT* pb = part + ((size_t)set * NBINS + bin) * BINCAP;
    cl[tid] = 0;
    __syncthreads();
    for (int j = tid; j < total; j += 256) {
        uintT v = pb[j];
        int loc = (v >> 16) & 255;
        int pos = atomicAdd(&cl[loc], 1);
        if (pos < CAP) bk[loc * CAP + pos] = (ushortT)(v & 0xFFFF);
    }
    __syncthreads();
    const int node0 = bin * BIN_NODES;
    int* cnt = set ? cnt_out : cnt_in;
    ushortT* bkt = set ? bkt_out : bkt_in;
    if (node0 + tid < N_NODES) cnt[node0 + tid] = cl[tid];
    const uint4* s4 = (const uint4*)bk;
    uint4* d4 = (uint4*)(bkt + (size_t)node0 * CAP);
    int lim = N_NODES - node0; if (lim > BIN_NODES) lim = BIN_NODES;
    lim = lim * (CAP / 8);                   // uint4 slots (8 ushorts each)
    for (int j = tid; j < lim; j += 256) d4[j] = s4[j];
}

// Mean-aggregate fp16 64-wide halves of P over fixed-cap buckets.
// One wave per (node, dir); 8 edges in flight (sub = lane>>3 picks edge,
// c = lane&7 picks 16B half8 chunk). fp32 accumulate, fp16 mean out.
__global__ __launch_bounds__(256) void pull_dual_kernel(
    const f16* __restrict__ P,
    const int* __restrict__ cnt_in, const ushortT* __restrict__ bkt_in,
    const int* __restrict__ cnt_out, const ushortT* __restrict__ bkt_out,
    f16* __restrict__ agg_in, f16* __restrict__ agg_out)
{
    int gid = blockIdx.x * blockDim.x + threadIdx.x;
    int wid = gid >> 6;
    const int lane = gid & 63;
    const int sub = lane >> 3;
    const int c = lane & 7;
    const int* cnt; const ushortT* bkt; f16* agg; int coloff;
    if (wid < N_NODES) { cnt = cnt_in; bkt = bkt_in; agg = agg_in; coloff = 0; }
    else { wid -= N_NODES; cnt = cnt_out; bkt = bkt_out; agg = agg_out; coloff = HALF; }
    const int node = rfl(wid);
    int deg = rfl(cnt[node]); if (deg > CAP) deg = CAP;
    const ushortT* row = bkt + (size_t)node * CAP;
    const f16* Pb = P + coloff + c * 8;
    float acc[8];
#pragma unroll
    for (int t = 0; t < 8; ++t) acc[t] = 0.0f;
    for (int j = 0; j < deg; j += 8) {
        int jc = j + sub;
        int idx = row[jc < deg ? jc : deg - 1];
        float m = (jc < deg) ? 1.0f : 0.0f;
        half8 v = *(const half8*)(Pb + (size_t)idx * D);
#pragma unroll
        for (int t = 0; t < 8; ++t) acc[t] = fmaf(m, (float)v[t], acc[t]);
    }
#pragma unroll
    for (int t = 0; t < 8; ++t) {
        acc[t] += __shfl_xor(acc[t], 8, 64);
        acc[t] += __shfl_xor(acc[t], 16, 64);
        acc[t] += __shfl_xor(acc[t], 32, 64);
    }
    if (sub == 0) {
        float inv = 1.0f / fmaxf((float)deg, 1.0f);
        half8 o;
#pragma unroll
        for (int t = 0; t < 8; ++t) o[t] = (f16)(acc[t] * inv);
        *(half8*)(agg + (size_t)node * HALF + c * 8) = o;
    }
}

// Fused MFMA SAGE layer. launch_bounds(256,3): ~170 VGPR cap -> NO scratch
// spill (round-9 pathology: VGPR=64 forced acc2/aX/aH to scratch; layer-1
// dispatch showed 25.6MB WRITE for a 0.2MB output). All global I/O routed
// through LDS as coalesced uint4; AG tile staged into Xw after aX extraction.
__global__ __launch_bounds__(256, 3) void fused_mfma_kernel(
    const float* __restrict__ Xf, const f16* __restrict__ X16,
    const f16* __restrict__ AGI, const f16* __restrict__ AGO,
    const f16* __restrict__ Wrp, const float* __restrict__ bl_in, const float* __restrict__ bl_out,
    const f16* __restrict__ cWp, const float* __restrict__ cb,
    f16* __restrict__ Xout16,
    const f16* __restrict__ Wlnp, f16* __restrict__ Pout,
    const float* __restrict__ fW, const float* __restrict__ fb, float* __restrict__ outv)
{
    __shared__ f16 Xh[4][16][D];   // per-wave: X tile -> AG tile -> X1 restage
    __shared__ f16 Hh[4][16][D];   // per-wave: H tile -> P restage
    const int tid = threadIdx.x, wave = tid >> 6, lane = tid & 63;
    const int nodeBase = blockIdx.x * M_BLK + wave * 16;
    f16 (*Xw)[D] = Xh[wave];
    f16 (*Hw)[D] = Hh[wave];
    const int colq = lane & 15;
    const int rq = lane >> 4;

    if (Xf) stage_f32(Xw, Xf, nodeBase, lane);
    else    stage_f16(Xw, X16, nodeBase, lane);

    half8 aX[4];
#pragma unroll
    for (int ks = 0; ks < 4; ++ks) aX[ks] = ldsA(Xw, lane, ks);

    // X tile fully captured in aX -> overwrite Xw with the AG tile (AGI|AGO),
    // coalesced uint4 loads, linear LDS layout (per-lane 32B reads later).
#pragma unroll
    for (int r = 0; r < 4; ++r) {
        int j = lane + 64 * r;
        int row = j >> 4, cc = j & 15;
        int nn = nodeBase + row; if (nn > N_NODES - 1) nn = N_NODES - 1;
        const f16* sp = (cc < 8) ? (AGI + (size_t)nn * HALF + cc * 8)
                                 : (AGO + (size_t)nn * HALF + (cc - 8) * 8);
        *(uint4*)&Xw[row][cc * 8] = *(const uint4*)sp;
    }

    // ---- conv: tiles ct<4 -> h_in cols, ct>=4 -> h_out cols ----
#pragma unroll
    for (int ct = 0; ct < 8; ++ct) {
        floatx4 acc = {0.f, 0.f, 0.f, 0.f};
#pragma unroll
        for (int ks = 0; ks < 4; ++ks) {
            half8 b = *(const half8*)(Wrp + (((ct * 4 + ks) * 64 + lane) << 3));
            acc = mfma16(aX[ks], b, acc);
        }
        int c64 = (ct & 3) * 16 + colq;
        int aoff = (ct < 4) ? 0 : HALF;
        float bl = (ct < 4) ? bl_in[c64] : bl_out[c64];
        int colg = ct * 16 + colq;
        int cc = colg >> 3;
#pragma unroll
        for (int i = 0; i < 4; ++i) {
            int r16 = rq * 4 + i;
            float h = acc[i] + (float)Xw[r16][aoff + c64] + bl;   // AG from LDS
            Hw[r16][((cc ^ (r16 & 7)) << 3) + (colg & 7)] = (f16)fmaxf(h, 0.f);
        }
    }

    // ---- combine: [X | H] @ cW + cb ----
    floatx4 acc2[8];
#pragma unroll
    for (int ct = 0; ct < 8; ++ct) {
        float cbv = cb[ct * 16 + colq];
        floatx4 t = {cbv, cbv, cbv, cbv};
#pragma unroll
        for (int ks = 0; ks < 4; ++ks) {
            half8 b = *(const half8*)(cWp + (((ct * 8 + ks) * 64 + lane) << 3));
            t = mfma16(aX[ks], b, t);
        }
        acc2[ct] = t;
    }
    half8 aH[4];
#pragma unroll
    for (int ks = 0; ks < 4; ++ks) aH[ks] = ldsA(Hw, lane, ks);
#pragma unroll
    for (int ct = 0; ct < 8; ++ct) {
#pragma unroll
        for (int ks = 0; ks < 4; ++ks) {
            half8 b = *(const half8*)(cWp + (((ct * 8 + 4 + ks) * 64 + lane) << 3));
            acc2[ct] = mfma16(aH[ks], b, acc2[ct]);
        }
    }

    if (fW == nullptr) {
        // X1 = relu(acc2) -> Xw swizzled (frees acc2), coalesced global store
#pragma unroll
        for (int ct = 0; ct < 8; ++ct) {
            int colg = ct * 16 + colq;
            int cc = colg >> 3;
#pragma unroll
            for (int i = 0; i < 4; ++i) {
                int r16 = rq * 4 + i;
                Xw[r16][((cc ^ (r16 & 7)) << 3) + (colg & 7)] = (f16)fmaxf(acc2[ct][i], 0.f);
            }
        }
#pragma unroll
        for (int r = 0; r < 4; ++r) {
            int j = lane + 64 * r;
            int row = j >> 4, cc = j & 15;
            int nn = nodeBase + row;
            if (nn < N_NODES)
                *(uint4*)(Xout16 + (size_t)nn * D + cc * 8) =
                    *(const uint4*)&Xw[row][((cc ^ (row & 7)) << 3)];
        }
        // next-layer transform: P = X1 @ Wln, results via Hw, coalesced store
        half8 a2[4];
#pragma unroll
        for (int ks = 0; ks < 4; ++ks) a2[ks] = ldsA(Xw, lane, ks);
#pragma unroll
        for (int ct = 0; ct < 8; ++ct) {
            floatx4 acc = {0.f, 0.f, 0.f, 0.f};
#pragma unroll
            for (int ks = 0; ks < 4; ++ks) {
                half8 b = *(const half8*)(Wlnp + (((ct * 4 + ks) * 64 + lane) << 3));
                acc = mfma16(a2[ks], b, acc);
            }
            int colg = ct * 16 + colq;
            int cc = colg >> 3;
#pragma unroll
            for (int i = 0; i < 4; ++i) {
                int r16 = rq * 4 + i;
                Hw[r16][((cc ^ (r16 & 7)) << 3) + (colg & 7)] = (f16)acc[i];
            }
        }
#pragma unroll
        for (int r = 0; r < 4; ++r) {
            int j = lane + 64 * r;
            int row = j >> 4, cc = j & 15;
            int nn = nodeBase + row;
            if (nn < N_NODES)
                *(uint4*)(Pout + (size_t)nn * D + cc * 8) =
                    *(const uint4*)&Hw[row][((cc ^ (row & 7)) << 3)];
        }
    } else {
        // final head: out[node] = sum_c relu(X2[node][c]) * fW[c] + fb
        float fs0 = 0, fs1 = 0, fs2 = 0, fs3 = 0;
#pragma unroll
        for (int ct = 0; ct < 8; ++ct) {
            float fwv = fW[ct * 16 + colq];
            fs0 = fmaf(fmaxf(acc2[ct][0], 0.f), fwv, fs0);
            fs1 = fmaf(fmaxf(acc2[ct][1], 0.f), fwv, fs1);
            fs2 = fmaf(fmaxf(acc2[ct][2], 0.f), fwv, fs2);
            fs3 = fmaf(fmaxf(acc2[ct][3], 0.f), fwv, fs3);
        }
#pragma unroll
        for (int off = 1; off < 16; off <<= 1) {
            fs0 += __shfl_xor(fs0, off, 64);
            fs1 += __shfl_xor(fs1, off, 64);
            fs2 += __shfl_xor(fs2, off, 64);
            fs3 += __shfl_xor(fs3, off, 64);
        }
        if (colq == 0) {
            float fbv = fb[0];
            int nb = nodeBase + rq * 4;
            if (nb + 0 < N_NODES) outv[nb + 0] = fs0 + fbv;
            if (nb + 1 < N_NODES) outv[nb + 1] = fs1 + fbv;
            if (nb + 2 < N_NODES) outv[nb + 2] = fs2 + fbv;
            if (nb + 3 < N_NODES) outv[nb + 3] = fs3 + fbv;
        }
    }
}

extern "C" void kernel_launch(void* const* d_in, const int* in_sizes, int n_in,
                              void* d_out, int out_size, void* d_ws, size_t ws_size,
                              hipStream_t stream) {
    const float* x       = (const float*)d_in[0];
    const int*   ei_in   = (const int*)d_in[1];
    const int*   ei_out  = (const int*)d_in[2];
    const float* in_Wl0  = (const float*)d_in[3];
    const float* in_bl0  = (const float*)d_in[4];
    const float* in_Wr0  = (const float*)d_in[5];
    const float* out_Wl0 = (const float*)d_in[6];
    const float* out_bl0 = (const float*)d_in[7];
    const float* out_Wr0 = (const float*)d_in[8];
    const float* comb_W0 = (const float*)d_in[9];
    const float* comb_b0 = (const float*)d_in[10];
    const float* in_Wl1  = (const float*)d_in[11];
    const float* in_bl1  = (const float*)d_in[12];
    const float* in_Wr1  = (const float*)d_in[13];
    const float* out_Wl1 = (const float*)d_in[14];
    const float* out_bl1 = (const float*)d_in[15];
    const float* out_Wr1 = (const float*)d_in[16];
    const float* comb_W1 = (const float*)d_in[17];
    const float* comb_b1 = (const float*)d_in[18];
    const float* final_W = (const float*)d_in[19];
    const float* final_b = (const float*)d_in[20];
    float* out = (float*)d_out;

    char* wsb = (char*)d_ws;
    size_t off = 0;
    auto take = [&](size_t sz) -> char* {
        char* p = wsb + off;
        off += (sz + 255) & ~(size_t)255;
        return p;
    };
    f16* AGI       = (f16*)take((size_t)N_NODES * HALF * 2);
    f16* AGO       = (f16*)take((size_t)N_NODES * HALF * 2);
    f16* X1h       = (f16*)take((size_t)N_NODES * D * 2);
    f16* P         = (f16*)take((size_t)N_NODES * D * 2);
    int* cnt_in    = (int*)take((size_t)2 * N_NODES * 4);   // cnt_in | cnt_out contiguous
    int* cnt_out   = cnt_in + N_NODES;
    ushortT* bkt_in  = (ushortT*)take((size_t)N_NODES * CAP * 2);
    ushortT* bkt_out = (ushortT*)take((size_t)N_NODES * CAP * 2);
    int* gcur      = (int*)take((size_t)2 * NBINS * 4);
    uintT* part    = (uintT*)take((size_t)2 * NBINS * BINCAP * 4);   // 6.4 MB
    f16* Wr0p = (f16*)take(32768);
    f16* Wl1p = (f16*)take(32768);
    f16* Wr1p = (f16*)take(32768);
    f16* Wl0p = (f16*)take(32768);
    f16* cW0p = (f16*)take(65536);
    f16* cW1p = (f16*)take(65536);

    const dim3 blk(256);
    const int pull_grid = (2 * N_NODES * 64) / 256;   // 25000, exact

    // ---- prep: zero bin cursors + pack all weights to fragment order ----
    prep_kernel<<<128, blk, 0, stream>>>(
        gcur,
        in_Wr0, out_Wr0, in_Wl1, out_Wl1, in_Wr1, out_Wr1, in_Wl0, out_Wl0,
        comb_W0, comb_W1,
        Wr0p, Wl1p, Wr1p, Wl0p, cW0p, cW1p);

    // ---- phase-A radix partition (LDS-privatized) + layer-0 P transform ----
    part_transform_kernel<<<PARTA_GRID + NODE64_GRID, blk, 0, stream>>>(
        ei_in, ei_out, gcur, part, x, Wl0p, P);

    // ---- phase-B: coalesced bucket build from partitioned edges ----
    bucket_build_kernel<<<2 * NBINS, blk, 0, stream>>>(
        part, gcur, cnt_in, cnt_out, bkt_in, bkt_out);

    // ---- layer 0 (fused kernel also emits layer-1 P) ----
    pull_dual_kernel<<<pull_grid, blk, 0, stream>>>(P, cnt_in, bkt_in, cnt_out, bkt_out, AGI, AGO);
    fused_mfma_kernel<<<NODE64_GRID, blk, 0, stream>>>(
        x, nullptr, AGI, AGO, Wr0p, in_bl0, out_bl0, cW0p, comb_b0,
        X1h, Wl1p, P, nullptr, nullptr, nullptr);

    // ---- layer 1 (+ fused final head) ----
    pull_dual_kernel<<<pull_grid, blk, 0, stream>>>(P, cnt_in, bkt_in, cnt_out, bkt_out, AGI, AGO);
    fused_mfma_kernel<<<NODE64_GRID, blk, 0, stream>>>(
        nullptr, X1h, AGI, AGO, Wr1p, in_bl1, out_bl1, cW1p, comb_b1,
        nullptr, nullptr, nullptr, final_W, final_b, out);
}

// Round 11
// 151.455 us; speedup vs baseline: 1.2703x; 1.2703x over previous
//
#include <hip/hip_runtime.h>
#include <hip/hip_fp16.h>

#define N_NODES 50000
#define D 128
#define HALF 64
#define E_EDGES 625000
#define CAP 64                                       // bucket capacity (max deg ~35)
#define M_BLK 64
#define NODE64_GRID ((N_NODES + M_BLK - 1) / M_BLK)  // 782 (transform part)
#define FUSED_GRID ((N_NODES + 31) / 32)             // 1563 (fused: 32 nodes/block)

// --- radix partition geometry ---
#define NBINS 196                                    // bins of 256 nodes: bin = dst>>8
#define BIN_NODES 256
#define BINCAP 4096                                  // per-bin capacity (mean ~3200, +14 sigma)
#define GA 98                                        // partition blocks per edge set
#define CHUNK ((E_EDGES + GA - 1) / GA)              // 6379 edges per block
#define PARTA_GRID (2 * GA)                          // 196

typedef unsigned short ushortT;
typedef unsigned int uintT;
using f16     = _Float16;
using half8   = __attribute__((ext_vector_type(8))) _Float16;
using half4v  = __attribute__((ext_vector_type(4))) _Float16;
using floatx4 = __attribute__((ext_vector_type(4))) float;

__device__ __forceinline__ int rfl(int v) { return __builtin_amdgcn_readfirstlane(v); }
__device__ __forceinline__ floatx4 mfma16(half8 a, half8 b, floatx4 c) {
    return __builtin_amdgcn_mfma_f32_16x16x32_f16(a, b, c, 0, 0, 0);
}

// A-fragment read from swizzled LDS tile [16 rows][128 f16].
// Swizzle: 16B chunk cc stored at chunk (cc ^ (row&7)).
__device__ __forceinline__ half8 ldsA(const f16 (*Xw)[D], int lane, int ks) {
    int r = lane & 15;
    int cc = ks * 4 + (lane >> 4);
    return *(const half8*)&Xw[r][((cc ^ (r & 7)) << 3)];
}

// Stage 16 fp32 rows -> fp16 swizzled LDS (one full wave).
__device__ __forceinline__ void stage_f32(f16 (*Xw)[D], const float* __restrict__ X,
                                          int nodeBase, int lane) {
#pragma unroll
    for (int r4 = 0; r4 < 8; ++r4) {
        int s = lane + 64 * r4;            // 512 float4 slots = 16 rows x 32
        int row = s >> 5, c4 = s & 31;
        int nn = nodeBase + row; if (nn > N_NODES - 1) nn = N_NODES - 1;
        float4 v = *(const float4*)(X + (size_t)nn * D + c4 * 4);
        int cc = c4 >> 1;
        half4v pk = { (f16)v.x, (f16)v.y, (f16)v.z, (f16)v.w };
        *(half4v*)&Xw[row][((cc ^ (row & 7)) << 3) + ((c4 & 1) << 2)] = pk;
    }
}

// Stage HALF a tile (8 fp32 rows, rows [t*8, t*8+8)) per wave.
__device__ __forceinline__ void stage_f32_half(f16 (*Xw)[D], const float* __restrict__ X,
                                               int nodeBase, int lane, int t) {
#pragma unroll
    for (int r4 = 0; r4 < 4; ++r4) {
        int s = lane + 64 * r4;            // 256 float4 slots = 8 rows x 32
        int row = t * 8 + (s >> 5), c4 = s & 31;
        int nn = nodeBase + row; if (nn > N_NODES - 1) nn = N_NODES - 1;
        float4 v = *(const float4*)(X + (size_t)nn * D + c4 * 4);
        int cc = c4 >> 1;
        half4v pk = { (f16)v.x, (f16)v.y, (f16)v.z, (f16)v.w };
        *(half4v*)&Xw[row][((cc ^ (row & 7)) << 3) + ((c4 & 1) << 2)] = pk;
    }
}

// Stage HALF a tile (8 fp16 rows) per wave.
__device__ __forceinline__ void stage_f16_half(f16 (*Xw)[D], const f16* __restrict__ X,
                                               int nodeBase, int lane, int t) {
#pragma unroll
    for (int r = 0; r < 2; ++r) {
        int s = lane + 64 * r;             // 128 chunk slots = 8 rows x 16
        int row = t * 8 + (s >> 4), cc = s & 15;
        int nn = nodeBase + row; if (nn > N_NODES - 1) nn = N_NODES - 1;
        uint4 v = *(const uint4*)(X + (size_t)nn * D + cc * 8);
        *(uint4*)&Xw[row][((cc ^ (row & 7)) << 3)] = v;
    }
}

// GEMM [16 x 128] = LDS-X @ packed-W(K=128), write fp16 result to Pout.
// (used by the co-scheduled transform in part_transform_kernel)
__device__ __forceinline__ void gemm_store_P(const f16 (*Xw)[D], const f16* __restrict__ Wp,
                                             f16* __restrict__ Pout, int nodeBase, int lane) {
    half8 a[4];
#pragma unroll
    for (int ks = 0; ks < 4; ++ks) a[ks] = ldsA(Xw, lane, ks);
#pragma unroll
    for (int ct = 0; ct < 8; ++ct) {
        floatx4 acc = {0.f, 0.f, 0.f, 0.f};
#pragma unroll
        for (int ks = 0; ks < 4; ++ks) {
            half8 b = *(const half8*)(Wp + (((ct * 4 + ks) * 64 + lane) << 3));
            acc = mfma16(a[ks], b, acc);
        }
        int col = ct * 16 + (lane & 15);
#pragma unroll
        for (int i = 0; i < 4; ++i) {
            int nn = nodeBase + (lane >> 4) * 4 + i;
            if (nn < N_NODES) Pout[(size_t)nn * D + col] = (f16)acc[i];
        }
    }
}

// prep: blocks 0..63 zero the 2*NBINS bin cursors; blocks 64..127 pack all six
// weight matrices into MFMA B-fragment order.
__global__ __launch_bounds__(256) void prep_kernel(
    int* __restrict__ gcur,
    const float* iWr0, const float* oWr0, const float* iWl1, const float* oWl1,
    const float* iWr1, const float* oWr1, const float* iWl0, const float* oWl0,
    const float* cW0, const float* cW1,
    f16* Wr0p, f16* Wl1p, f16* Wr1p, f16* Wl0p, f16* cW0p, f16* cW1p)
{
    int b = blockIdx.x;
    if (b < 64) {
        for (int i = b * 256 + threadIdx.x; i < 2 * NBINS; i += 64 * 256) gcur[i] = 0;
        return;
    }
    b -= 64;
    if (b < 32) {   // dual K=128 packs: 4 weights x 8 blocks
        int w = b >> 3;
        int e = (b & 7) * 256 + threadIdx.x;          // [0, 2048)
        const float* Wa; const float* Wb; f16* dst;
        if (w == 0)      { Wa = iWr0; Wb = oWr0; dst = Wr0p; }
        else if (w == 1) { Wa = iWl1; Wb = oWl1; dst = Wl1p; }
        else if (w == 2) { Wa = iWr1; Wb = oWr1; dst = Wr1p; }
        else             { Wa = iWl0; Wb = oWl0; dst = Wl0p; }
        int lane = e & 63, ks = (e >> 6) & 3, ct = e >> 8;
        int k0 = ks * 32 + ((lane >> 4) << 3), c = ct * 16 + (lane & 15);
        half8 v;
#pragma unroll
        for (int j = 0; j < 8; ++j) {
            int k = k0 + j;
            float f = (c < 64) ? Wa[k * HALF + c] : Wb[k * HALF + (c - 64)];
            v[j] = (f16)f;
        }
        *(half8*)(dst + ((size_t)e << 3)) = v;
        return;
    }
    b -= 32;        // cW K=256 packs: 2 weights x 16 blocks
    {
        int w = b >> 4;
        int e = (b & 15) * 256 + threadIdx.x;         // [0, 4096)
        const float* W = w ? cW1 : cW0;
        f16* dst = w ? cW1p : cW0p;
        int lane = e & 63, ks = (e >> 6) & 7, ct = e >> 9;
        int k0 = ks * 32 + ((lane >> 4) << 3), c = ct * 16 + (lane & 15);
        half8 v;
#pragma unroll
        for (int j = 0; j < 8; ++j) v[j] = (f16)W[(size_t)(k0 + j) * D + c];
        *(half8*)(dst + ((size_t)e << 3)) = v;
    }
}

// Heterogeneous launch:
//  blocks [0, PARTA_GRID): phase-A radix partition of one edge-set chunk.
//  blocks [PARTA_GRID, +NODE64_GRID): MFMA transform P = X @ Wl0 (fp16).
__global__ __launch_bounds__(256) void part_transform_kernel(
    const int* __restrict__ ei_in, const int* __restrict__ ei_out,
    int* __restrict__ gcur, uintT* __restrict__ part,
    const float* __restrict__ X, const f16* __restrict__ Wl0p, f16* __restrict__ P)
{
    __shared__ __align__(16) char lraw[28032];
    const int tid = threadIdx.x;
    if ((int)blockIdx.x < PARTA_GRID) {
        uintT* le   = (uintT*)lraw;                       // 6400 x 4B
        int* cnt_l  = (int*)(lraw + 25600);               // 196
        int* base_l = cnt_l + NBINS;
        int* run_l  = base_l + NBINS;
        const int set = (int)blockIdx.x >= GA;
        const int b = blockIdx.x - (set ? GA : 0);
        const int* ei = set ? ei_out : ei_in;
        const int e0 = b * CHUNK;
        int n = E_EDGES - e0; if (n > CHUNK) n = CHUNK; if (n < 0) n = 0;
        for (int j = tid; j < n; j += 256) {
            int src = ei[e0 + j];
            int dst = ei[E_EDGES + e0 + j];
            le[j] = ((uintT)dst << 16) | (uintT)src;      // both < 2^16
        }
        for (int j = tid; j < NBINS; j += 256) cnt_l[j] = 0;
        __syncthreads();
        for (int j = tid; j < n; j += 256) atomicAdd(&cnt_l[le[j] >> 24], 1);  // bin = dst>>8
        __syncthreads();
        for (int j = tid; j < NBINS; j += 256) {
            int c = cnt_l[j];
            base_l[j] = c ? atomicAdd(&gcur[set * NBINS + j], c) : 0;
            run_l[j] = 0;
        }
        __syncthreads();
        uintT* pbase = part + (size_t)set * NBINS * BINCAP;
        for (int j = tid; j < n; j += 256) {
            uintT v = le[j];
            int bin = v >> 24;
            int pos = base_l[bin] + atomicAdd(&run_l[bin], 1);
            if (pos < BINCAP) pbase[(size_t)bin * BINCAP + pos] = v;
        }
        return;
    }
    // ---- transform part ----
    f16 (*Xh)[16][D] = (f16(*)[16][D])lraw;               // 4 x 16 x 128 f16 = 16 KB
    const int bid = blockIdx.x - PARTA_GRID;
    const int wave = tid >> 6, lane = tid & 63;
    const int nodeBase = bid * M_BLK + wave * 16;
    f16 (*Xw)[D] = Xh[wave];
    stage_f32(Xw, X, nodeBase, lane);
    gemm_store_P(Xw, Wl0p, P, nodeBase, lane);
}

// Phase B: one block per (bin, set). Build the 256-node bucket tile in LDS
// (LDS atomics only), then write counts + 32 KB tile fully coalesced.
__global__ __launch_bounds__(256) void bucket_build_kernel(
    const uintT* __restrict__ part, const int* __restrict__ gcur,
    int* __restrict__ cnt_in, int* __restrict__ cnt_out,
    ushortT* __restrict__ bkt_in, ushortT* __restrict__ bkt_out)
{
    __shared__ ushortT bk[BIN_NODES * CAP];   // 32 KB
    __shared__ int cl[BIN_NODES];
    const int tid = threadIdx.x;
    const int set = (int)blockIdx.x >= NBINS;
    const int bin = blockIdx.x - (set ? NBINS : 0);
    int total = gcur[set * NBINS + bin]; if (total > BINCAP) total = BINCAP;
    const uintT* pb = part + ((size_t)set * NBINS + bin) * BINCAP;
    cl[tid] = 0;
    __syncthreads();
    for (int j = tid; j < total; j += 256) {
        uintT v = pb[j];
        int loc = (v >> 16) & 255;
        int pos = atomicAdd(&cl[loc], 1);
        if (pos < CAP) bk[loc * CAP + pos] = (ushortT)(v & 0xFFFF);
    }
    __syncthreads();
    const int node0 = bin * BIN_NODES;
    int* cnt = set ? cnt_out : cnt_in;
    ushortT* bkt = set ? bkt_out : bkt_in;
    if (node0 + tid < N_NODES) cnt[node0 + tid] = cl[tid];
    const uint4* s4 = (const uint4*)bk;
    uint4* d4 = (uint4*)(bkt + (size_t)node0 * CAP);
    int lim = N_NODES - node0; if (lim > BIN_NODES) lim = BIN_NODES;
    lim = lim * (CAP / 8);                   // uint4 slots (8 ushorts each)
    for (int j = tid; j < lim; j += 256) d4[j] = s4[j];
}

// Mean-aggregate fp16 64-wide halves of P over fixed-cap buckets.
__global__ __launch_bounds__(256) void pull_dual_kernel(
    const f16* __restrict__ P,
    const int* __restrict__ cnt_in, const ushortT* __restrict__ bkt_in,
    const int* __restrict__ cnt_out, const ushortT* __restrict__ bkt_out,
    f16* __restrict__ agg_in, f16* __restrict__ agg_out)
{
    int gid = blockIdx.x * blockDim.x + threadIdx.x;
    int wid = gid >> 6;
    const int lane = gid & 63;
    const int sub = lane >> 3;
    const int c = lane & 7;
    const int* cnt; const ushortT* bkt; f16* agg; int coloff;
    if (wid < N_NODES) { cnt = cnt_in; bkt = bkt_in; agg = agg_in; coloff = 0; }
    else { wid -= N_NODES; cnt = cnt_out; bkt = bkt_out; agg = agg_out; coloff = HALF; }
    const int node = rfl(wid);
    int deg = rfl(cnt[node]); if (deg > CAP) deg = CAP;
    const ushortT* row = bkt + (size_t)node * CAP;
    const f16* Pb = P + coloff + c * 8;
    float acc[8];
#pragma unroll
    for (int t = 0; t < 8; ++t) acc[t] = 0.0f;
    for (int j = 0; j < deg; j += 8) {
        int jc = j + sub;
        int idx = row[jc < deg ? jc : deg - 1];
        float m = (jc < deg) ? 1.0f : 0.0f;
        half8 v = *(const half8*)(Pb + (size_t)idx * D);
#pragma unroll
        for (int t = 0; t < 8; ++t) acc[t] = fmaf(m, (float)v[t], acc[t]);
    }
#pragma unroll
    for (int t = 0; t < 8; ++t) {
        acc[t] += __shfl_xor(acc[t], 8, 64);
        acc[t] += __shfl_xor(acc[t], 16, 64);
        acc[t] += __shfl_xor(acc[t], 32, 64);
    }
    if (sub == 0) {
        float inv = 1.0f / fmaxf((float)deg, 1.0f);
        half8 o;
#pragma unroll
        for (int t = 0; t < 8; ++t) o[t] = (f16)(acc[t] * inv);
        *(half8*)(agg + (size_t)node * HALF + c * 8) = o;
    }
}

// Fused MFMA SAGE layer — COLUMN-SPLIT wave teams (round-11 change).
// Block = 4 waves, 32 nodes. Wave pair (rg = wave>>1) owns 16 rows; within a
// pair, wave t = wave&1 computes column-half [t*64, t*64+64) of conv, combine,
// and P. X/H tiles are pair-shared LDS (3 syncthreads). Doubles wave count
// (6250 waves, ~24/CU vs 12) for latency hiding; acc2 halves to 4 regs-of-4.
// Otherwise byte-identical structure to the proven round-9 kernel.
__global__ __launch_bounds__(256) void fused_mfma_kernel(
    const float* __restrict__ Xf, const f16* __restrict__ X16,
    const f16* __restrict__ AGI, const f16* __restrict__ AGO,
    const f16* __restrict__ Wrp, const float* __restrict__ bl_in, const float* __restrict__ bl_out,
    const f16* __restrict__ cWp, const float* __restrict__ cb,
    f16* __restrict__ Xout16,
    const f16* __restrict__ Wlnp, f16* __restrict__ Pout,
    const float* __restrict__ fW, const float* __restrict__ fb, float* __restrict__ outv)
{
    __shared__ f16 Xh[2][16][D];        // 8 KB: X tile per row-group (later X1)
    __shared__ f16 Hh[2][16][D];        // 8 KB: H tile per row-group
    __shared__ float fpart[2][2][16];   // final-head cross-wave partials
    const int tid = threadIdx.x, wave = tid >> 6, lane = tid & 63;
    const int rg = wave >> 1;           // row group (16 rows each)
    const int t  = wave & 1;            // column half
    const int nodeBase = blockIdx.x * 32 + rg * 16;
    f16 (*Xw)[D] = Xh[rg];
    f16 (*Hw)[D] = Hh[rg];
    const int colq = lane & 15;
    const int rq = lane >> 4;

    if (Xf) stage_f32_half(Xw, Xf, nodeBase, lane, t);
    else    stage_f16_half(Xw, X16, nodeBase, lane, t);
    __syncthreads();                    // X tile complete

    half8 aX[4];
#pragma unroll
    for (int ks = 0; ks < 4; ++ks) aX[ks] = ldsA(Xw, lane, ks);

    // ---- conv: this wave's 4 col-tiles (t=0 -> h_in cols, t=1 -> h_out) ----
#pragma unroll
    for (int ct4 = 0; ct4 < 4; ++ct4) {
        const int ct = t * 4 + ct4;
        floatx4 acc = {0.f, 0.f, 0.f, 0.f};
#pragma unroll
        for (int ks = 0; ks < 4; ++ks) {
            half8 b = *(const half8*)(Wrp + (((ct * 4 + ks) * 64 + lane) << 3));
            acc = mfma16(aX[ks], b, acc);
        }
        const int c64 = ct4 * 16 + colq;
        const f16* AG = t ? AGO : AGI;
        const float bl = t ? bl_out[c64] : bl_in[c64];
        const int colg = ct * 16 + colq;
        const int cc = colg >> 3;
#pragma unroll
        for (int i = 0; i < 4; ++i) {
            int r16 = rq * 4 + i;
            int nn = nodeBase + r16; if (nn > N_NODES - 1) nn = N_NODES - 1;
            float h = acc[i] + (float)AG[(size_t)nn * HALF + c64] + bl;
            Hw[r16][((cc ^ (r16 & 7)) << 3) + (colg & 7)] = (f16)fmaxf(h, 0.f);
        }
    }

    // ---- combine X-part BEFORE the H sync (hides cW fetch latency) ----
    floatx4 acc2[4];
#pragma unroll
    for (int ct4 = 0; ct4 < 4; ++ct4) {
        const int ct = t * 4 + ct4;
        float cbv = cb[ct * 16 + colq];
        floatx4 a = {cbv, cbv, cbv, cbv};
#pragma unroll
        for (int ks = 0; ks < 4; ++ks) {
            half8 b = *(const half8*)(cWp + (((ct * 8 + ks) * 64 + lane) << 3));
            a = mfma16(aX[ks], b, a);
        }
        acc2[ct4] = a;
    }
    __syncthreads();                    // H tile complete (both halves)

    half8 aH[4];
#pragma unroll
    for (int ks = 0; ks < 4; ++ks) aH[ks] = ldsA(Hw, lane, ks);
#pragma unroll
    for (int ct4 = 0; ct4 < 4; ++ct4) {
        const int ct = t * 4 + ct4;
#pragma unroll
        for (int ks = 0; ks < 4; ++ks) {
            half8 b = *(const half8*)(cWp + (((ct * 8 + 4 + ks) * 64 + lane) << 3));
            acc2[ct4] = mfma16(aH[ks], b, acc2[ct4]);
        }
    }

    if (fW == nullptr) {
        // X1 = relu(acc2): scalar global store + swizzled restage into Xw
#pragma unroll
        for (int ct4 = 0; ct4 < 4; ++ct4) {
            const int ct = t * 4 + ct4;
            const int colg = ct * 16 + colq;
            const int cc = colg >> 3;
#pragma unroll
            for (int i = 0; i < 4; ++i) {
                int r16 = rq * 4 + i;
                int nn = nodeBase + r16;
                f16 hv = (f16)fmaxf(acc2[ct4][i], 0.f);
                if (nn < N_NODES) Xout16[(size_t)nn * D + colg] = hv;
                Xw[r16][((cc ^ (r16 & 7)) << 3) + (colg & 7)] = hv;
            }
        }
        __syncthreads();                // X1 tile complete
        // next-layer transform: P = X1 @ Wln (this wave's col half)
        half8 a2[4];
#pragma unroll
        for (int ks = 0; ks < 4; ++ks) a2[ks] = ldsA(Xw, lane, ks);
#pragma unroll
        for (int ct4 = 0; ct4 < 4; ++ct4) {
            const int ct = t * 4 + ct4;
            floatx4 acc = {0.f, 0.f, 0.f, 0.f};
#pragma unroll
            for (int ks = 0; ks < 4; ++ks) {
                half8 b = *(const half8*)(Wlnp + (((ct * 4 + ks) * 64 + lane) << 3));
                acc = mfma16(a2[ks], b, acc);
            }
            const int col = ct * 16 + colq;
#pragma unroll
            for (int i = 0; i < 4; ++i) {
                int nn = nodeBase + rq * 4 + i;
                if (nn < N_NODES) Pout[(size_t)nn * D + col] = (f16)acc[i];
            }
        }
    } else {
        // final head: partial over this wave's 64 cols, combine via LDS
        float fs0 = 0, fs1 = 0, fs2 = 0, fs3 = 0;
#pragma unroll
        for (int ct4 = 0; ct4 < 4; ++ct4) {
            const int ct = t * 4 + ct4;
            float fwv = fW[ct * 16 + colq];
            fs0 = fmaf(fmaxf(acc2[ct4][0], 0.f), fwv, fs0);
            fs1 = fmaf(fmaxf(acc2[ct4][1], 0.f), fwv, fs1);
            fs2 = fmaf(fmaxf(acc2[ct4][2], 0.f), fwv, fs2);
            fs3 = fmaf(fmaxf(acc2[ct4][3], 0.f), fwv, fs3);
        }
#pragma unroll
        for (int off = 1; off < 16; off <<= 1) {
            fs0 += __shfl_xor(fs0, off, 64);
            fs1 += __shfl_xor(fs1, off, 64);
            fs2 += __shfl_xor(fs2, off, 64);
            fs3 += __shfl_xor(fs3, off, 64);
        }
        if (colq == 0) {
            fpart[rg][t][rq * 4 + 0] = fs0;
            fpart[rg][t][rq * 4 + 1] = fs1;
            fpart[rg][t][rq * 4 + 2] = fs2;
            fpart[rg][t][rq * 4 + 3] = fs3;
        }
        __syncthreads();
        if (t == 0 && lane < 16) {
            int nn = nodeBase + lane;
            if (nn < N_NODES)
                outv[nn] = fpart[rg][0][lane] + fpart[rg][1][lane] + fb[0];
        }
    }
}

extern "C" void kernel_launch(void* const* d_in, const int* in_sizes, int n_in,
                              void* d_out, int out_size, void* d_ws, size_t ws_size,
                              hipStream_t stream) {
    const float* x       = (const float*)d_in[0];
    const int*   ei_in   = (const int*)d_in[1];
    const int*   ei_out  = (const int*)d_in[2];
    const float* in_Wl0  = (const float*)d_in[3];
    const float* in_bl0  = (const float*)d_in[4];
    const float* in_Wr0  = (const float*)d_in[5];
    const float* out_Wl0 = (const float*)d_in[6];
    const float* out_bl0 = (const float*)d_in[7];
    const float* out_Wr0 = (const float*)d_in[8];
    const float* comb_W0 = (const float*)d_in[9];
    const float* comb_b0 = (const float*)d_in[10];
    const float* in_Wl1  = (const float*)d_in[11];
    const float* in_bl1  = (const float*)d_in[12];
    const float* in_Wr1  = (const float*)d_in[13];
    const float* out_Wl1 = (const float*)d_in[14];
    const float* out_bl1 = (const float*)d_in[15];
    const float* out_Wr1 = (const float*)d_in[16];
    const float* comb_W1 = (const float*)d_in[17];
    const float* comb_b1 = (const float*)d_in[18];
    const float* final_W = (const float*)d_in[19];
    const float* final_b = (const float*)d_in[20];
    float* out = (float*)d_out;

    char* wsb = (char*)d_ws;
    size_t off = 0;
    auto take = [&](size_t sz) -> char* {
        char* p = wsb + off;
        off += (sz + 255) & ~(size_t)255;
        return p;
    };
    f16* AGI       = (f16*)take((size_t)N_NODES * HALF * 2);
    f16* AGO       = (f16*)take((size_t)N_NODES * HALF * 2);
    f16* X1h       = (f16*)take((size_t)N_NODES * D * 2);
    f16* P         = (f16*)take((size_t)N_NODES * D * 2);
    int* cnt_in    = (int*)take((size_t)2 * N_NODES * 4);   // cnt_in | cnt_out contiguous
    int* cnt_out   = cnt_in + N_NODES;
    ushortT* bkt_in  = (ushortT*)take((size_t)N_NODES * CAP * 2);
    ushortT* bkt_out = (ushortT*)take((size_t)N_NODES * CAP * 2);
    int* gcur      = (int*)take((size_t)2 * NBINS * 4);
    uintT* part    = (uintT*)take((size_t)2 * NBINS * BINCAP * 4);   // 6.4 MB
    f16* Wr0p = (f16*)take(32768);
    f16* Wl1p = (f16*)take(32768);
    f16* Wr1p = (f16*)take(32768);
    f16* Wl0p = (f16*)take(32768);
    f16* cW0p = (f16*)take(65536);
    f16* cW1p = (f16*)take(65536);

    const dim3 blk(256);
    const int pull_grid = (2 * N_NODES * 64) / 256;   // 25000, exact

    // ---- prep: zero bin cursors + pack all weights to fragment order ----
    prep_kernel<<<128, blk, 0, stream>>>(
        gcur,
        in_Wr0, out_Wr0, in_Wl1, out_Wl1, in_Wr1, out_Wr1, in_Wl0, out_Wl0,
        comb_W0, comb_W1,
        Wr0p, Wl1p, Wr1p, Wl0p, cW0p, cW1p);

    // ---- phase-A radix partition (LDS-privatized) + layer-0 P transform ----
    part_transform_kernel<<<PARTA_GRID + NODE64_GRID, blk, 0, stream>>>(
        ei_in, ei_out, gcur, part, x, Wl0p, P);

    // ---- phase-B: coalesced bucket build from partitioned edges ----
    bucket_build_kernel<<<2 * NBINS, blk, 0, stream>>>(
        part, gcur, cnt_in, cnt_out, bkt_in, bkt_out);

    // ---- layer 0 (fused kernel also emits layer-1 P) ----
    pull_dual_kernel<<<pull_grid, blk, 0, stream>>>(P, cnt_in, bkt_in, cnt_out, bkt_out, AGI, AGO);
    fused_mfma_kernel<<<FUSED_GRID, blk, 0, stream>>>(
        x, nullptr, AGI, AGO, Wr0p, in_bl0, out_bl0, cW0p, comb_b0,
        X1h, Wl1p, P, nullptr, nullptr, nullptr);

    // ---- layer 1 (+ fused final head) ----
    pull_dual_kernel<<<pull_grid, blk, 0, stream>>>(P, cnt_in, bkt_in, cnt_out, bkt_out, AGI, AGO);
    fused_mfma_kernel<<<FUSED_GRID, blk, 0, stream>>>(
        nullptr, X1h, AGI, AGO, Wr1p, in_bl1, out_bl1, cW1p, comb_b1,
        nullptr, nullptr, nullptr, final_W, final_b, out);
}